// Round 1
// baseline (388.551 us; speedup 1.0000x reference)
//
#include <hip/hip_runtime.h>

// Problem constants: B=32, T=1024, IN=1024, OUT=1024
// M = B*T = 32768, K = IN = 1024, N = OUT = 1024
#define M_DIM 32768
#define N_DIM 1024
#define K_DIM 1024

typedef unsigned int uint32;
typedef __attribute__((ext_vector_type(8))) short short8;     // 8 bf16 = 4 VGPR (MFMA A/B frag)
typedef __attribute__((ext_vector_type(4))) float floatx4;    // MFMA C/D frag

__device__ __forceinline__ unsigned short f2bf(float f) {
    // round-to-nearest-even fp32 -> bf16 (inputs are finite)
    uint32 u = __float_as_uint(f);
    uint32 r = u + 0x7fffu + ((u >> 16) & 1u);
    return (unsigned short)(r >> 16);
}

__device__ __forceinline__ float bf2f(unsigned short h) {
    return __uint_as_float(((uint32)h) << 16);
}

__device__ __forceinline__ void async_load16(const void* g, void* s) {
    // global -> LDS direct, 16B per lane; LDS dest = wave-uniform base + lane*16
    __builtin_amdgcn_global_load_lds(
        (const __attribute__((address_space(1))) void*)g,
        (__attribute__((address_space(3))) void*)s,
        16, 0, 0);
}

// ---------------------------------------------------------------------------
// fp32 -> bf16 cast, 4 elems/thread
// ---------------------------------------------------------------------------
__global__ void cast_f32_bf16(const float* __restrict__ src,
                              unsigned short* __restrict__ dst, int n4) {
    int i = blockIdx.x * blockDim.x + threadIdx.x;
    if (i < n4) {
        float4 v = ((const float4*)src)[i];
        ushort4 o;
        o.x = f2bf(v.x); o.y = f2bf(v.y); o.z = f2bf(v.z); o.w = f2bf(v.w);
        ((ushort4*)dst)[i] = o;
    }
}

// ---------------------------------------------------------------------------
// bf16 MFMA GEMM: C[m,n] = sum_k A[m,k]*W[n,k] + bias[n]
// 128x128 tile, BK=64, 256 threads = 4 waves (2x2), each wave 4x4 of 16x16x32.
// LDS layout: row-major [row][8 chunks of 16B], chunk XOR-swizzled by (row&7)
// (swizzle folded into the *global source* address so global_load_lds's
//  contiguous lane->LDS mapping still works). Frag ds_read_b128 then hits all
//  32 banks across each 8-row group -> only the free 2-way aliasing.
// ---------------------------------------------------------------------------
__global__ __launch_bounds__(256) void gemm_mfma(
    const unsigned short* __restrict__ A,   // [M, K] bf16
    const unsigned short* __restrict__ Bw,  // [N, K] bf16
    const float* __restrict__ bias,         // [N]
    unsigned short* outBf,                  // [M, N] bf16 (or null)
    float* outF) {                          // [M, N] fp32 (or null)
    __shared__ unsigned short As[128 * 64];
    __shared__ unsigned short Bs[128 * 64];

    const int tid  = threadIdx.x;
    const int lane = tid & 63;
    const int wid  = tid >> 6;
    const int l15  = lane & 15;
    const int quad = lane >> 4;
    const int wm   = wid >> 1;     // wave row (0..1)
    const int wn   = wid & 1;      // wave col (0..1)
    const int bm0  = blockIdx.y * 128;
    const int bn0  = blockIdx.x * 128;

    floatx4 acc[4][4];
#pragma unroll
    for (int i = 0; i < 4; ++i)
#pragma unroll
        for (int j = 0; j < 4; ++j)
            acc[i][j] = (floatx4){0.f, 0.f, 0.f, 0.f};

    for (int kt = 0; kt < K_DIM / 64; ++kt) {
        const int k0 = kt * 64;
        // stage A tile: 1024 slots of 16B; thread handles 4 slots
#pragma unroll
        for (int q = 0; q < 4; ++q) {
            int slot = q * 256 + tid;
            int row  = slot >> 3;
            int ch   = slot & 7;
            int sc   = ch ^ (row & 7);   // XOR swizzle via source address
            async_load16(A + (size_t)(bm0 + row) * K_DIM + k0 + sc * 8,
                         &As[(q * 256 + wid * 64) * 8]);
        }
#pragma unroll
        for (int q = 0; q < 4; ++q) {
            int slot = q * 256 + tid;
            int row  = slot >> 3;
            int ch   = slot & 7;
            int sc   = ch ^ (row & 7);
            async_load16(Bw + (size_t)(bn0 + row) * K_DIM + k0 + sc * 8,
                         &Bs[(q * 256 + wid * 64) * 8]);
        }
        __syncthreads();   // drains vmcnt -> LDS valid

#pragma unroll
        for (int ks = 0; ks < 2; ++ks) {
            short8 af[4], bfr[4];
#pragma unroll
            for (int i = 0; i < 4; ++i) {
                int r = wm * 64 + i * 16 + l15;        // A row (m)
                int c = ks * 4 + quad;                 // 16B chunk along k
                af[i] = *(const short8*)&As[r * 64 + ((c ^ (r & 7)) * 8)];
            }
#pragma unroll
            for (int j = 0; j < 4; ++j) {
                int r = wn * 64 + j * 16 + l15;        // B row (n)
                int c = ks * 4 + quad;
                bfr[j] = *(const short8*)&Bs[r * 64 + ((c ^ (r & 7)) * 8)];
            }
#pragma unroll
            for (int i = 0; i < 4; ++i)
#pragma unroll
                for (int j = 0; j < 4; ++j)
                    acc[i][j] = __builtin_amdgcn_mfma_f32_16x16x32_bf16(
                        af[i], bfr[j], acc[i][j], 0, 0, 0);
        }
        __syncthreads();   // protect LDS before next stage
    }

    // Epilogue. C/D layout (verified m89/m91): col = lane&15, row = quad*4 + reg
#pragma unroll
    for (int j = 0; j < 4; ++j) {
        int col = bn0 + wn * 64 + j * 16 + l15;
        float bb = bias[col];
#pragma unroll
        for (int i = 0; i < 4; ++i) {
            int rowb = bm0 + wm * 64 + i * 16 + quad * 4;
#pragma unroll
            for (int r = 0; r < 4; ++r) {
                float v = acc[i][j][r] + bb;
                size_t idx = (size_t)(rowb + r) * N_DIM + col;
                if (outBf) outBf[idx] = f2bf(v);
                else       outF[idx]  = v;
            }
        }
    }
}

// ---------------------------------------------------------------------------
// Leaky-integrator scan over T. One thread per (b, o) sequence.
// u_t = a*u_{t-1} + (1-a)*x_t.  Unroll 16 -> 16 independent loads in flight.
// ---------------------------------------------------------------------------
__global__ void scan_bf16(const unsigned short* __restrict__ cur,
                          const float* __restrict__ decay,
                          float* __restrict__ out) {
    int tid = blockIdx.x * 64 + threadIdx.x;     // 0..32767
    int o = tid & (N_DIM - 1);
    size_t base = ((size_t)(tid >> 10) << 20) + o;   // b*T*N + o
    float a = decay[o];
    float c = 1.f - a;
    float u = 0.f;
    for (int t0 = 0; t0 < 1024; t0 += 16) {
        float x[16];
#pragma unroll
        for (int k = 0; k < 16; ++k)
            x[k] = bf2f(cur[base + (size_t)(t0 + k) * N_DIM]);
#pragma unroll
        for (int k = 0; k < 16; ++k) {
            u = a * u + c * x[k];
            out[base + (size_t)(t0 + k) * N_DIM] = u;
        }
    }
}

__global__ void scan_f32_inplace(float* __restrict__ buf,
                                 const float* __restrict__ decay) {
    int tid = blockIdx.x * 64 + threadIdx.x;
    int o = tid & (N_DIM - 1);
    size_t base = ((size_t)(tid >> 10) << 20) + o;
    float a = decay[o];
    float c = 1.f - a;
    float u = 0.f;
    for (int t0 = 0; t0 < 1024; t0 += 16) {
        float x[16];
#pragma unroll
        for (int k = 0; k < 16; ++k)
            x[k] = buf[base + (size_t)(t0 + k) * N_DIM];
#pragma unroll
        for (int k = 0; k < 16; ++k) {
            u = a * u + c * x[k];
            buf[base + (size_t)(t0 + k) * N_DIM] = u;
        }
    }
}

// ---------------------------------------------------------------------------
// Fallback naive fp32 GEMM (only if workspace too small for the bf16 path)
// ---------------------------------------------------------------------------
__global__ void gemm_naive(const float* __restrict__ X, const float* __restrict__ W,
                           const float* __restrict__ bias, float* __restrict__ out) {
    __shared__ float As[16][17], Bs[16][17];
    int tx = threadIdx.x, ty = threadIdx.y;
    int m0 = blockIdx.y * 16, n0 = blockIdx.x * 16;
    float acc = 0.f;
    for (int k0 = 0; k0 < K_DIM; k0 += 16) {
        As[ty][tx] = X[(size_t)(m0 + ty) * K_DIM + k0 + tx];
        Bs[ty][tx] = W[(size_t)(n0 + ty) * K_DIM + k0 + tx];
        __syncthreads();
#pragma unroll
        for (int kk = 0; kk < 16; ++kk) acc += As[ty][kk] * Bs[tx][kk];
        __syncthreads();
    }
    out[(size_t)(m0 + ty) * N_DIM + n0 + tx] = acc + bias[n0 + tx];
}

// ---------------------------------------------------------------------------
extern "C" void kernel_launch(void* const* d_in, const int* in_sizes, int n_in,
                              void* d_out, int out_size, void* d_ws, size_t ws_size,
                              hipStream_t stream) {
    const float* X     = (const float*)d_in[0];  // [B,T,IN]  = [M,K]
    const float* Wt    = (const float*)d_in[1];  // [OUT,IN]  = [N,K]
    const float* bias  = (const float*)d_in[2];  // [OUT]
    const float* decay = (const float*)d_in[3];  // [OUT]
    float* out = (float*)d_out;                  // [B,T,OUT] = [M,N]

    const size_t A_bytes = (size_t)M_DIM * K_DIM * 2;   // 64 MB
    const size_t W_bytes = (size_t)N_DIM * K_DIM * 2;   // 2 MB
    const size_t C_bytes = (size_t)M_DIM * N_DIM * 2;   // 64 MB
    const size_t need_mid  = A_bytes + W_bytes;             // 66 MB
    const size_t need_full = A_bytes + W_bytes + C_bytes;   // 130 MB

    if (ws_size >= need_full) {
        unsigned short* Abf = (unsigned short*)d_ws;
        unsigned short* Wbf = (unsigned short*)((char*)d_ws + A_bytes);
        unsigned short* Cbf = (unsigned short*)((char*)d_ws + A_bytes + W_bytes);
        cast_f32_bf16<<<(M_DIM * K_DIM / 4 + 255) / 256, 256, 0, stream>>>(X, Abf, M_DIM * K_DIM / 4);
        cast_f32_bf16<<<(N_DIM * K_DIM / 4 + 255) / 256, 256, 0, stream>>>(Wt, Wbf, N_DIM * K_DIM / 4);
        gemm_mfma<<<dim3(N_DIM / 128, M_DIM / 128), 256, 0, stream>>>(Abf, Wbf, bias, Cbf, nullptr);
        scan_bf16<<<(M_DIM * N_DIM / K_DIM) / 64 / 16 * 16 + 0, 64, 0, stream>>>(Cbf, decay, out);
        // grid above: 32*1024/64 = 512 blocks
    } else if (ws_size >= need_mid) {
        unsigned short* Abf = (unsigned short*)d_ws;
        unsigned short* Wbf = (unsigned short*)((char*)d_ws + A_bytes);
        cast_f32_bf16<<<(M_DIM * K_DIM / 4 + 255) / 256, 256, 0, stream>>>(X, Abf, M_DIM * K_DIM / 4);
        cast_f32_bf16<<<(N_DIM * K_DIM / 4 + 255) / 256, 256, 0, stream>>>(Wt, Wbf, N_DIM * K_DIM / 4);
        gemm_mfma<<<dim3(N_DIM / 128, M_DIM / 128), 256, 0, stream>>>(Abf, Wbf, bias, nullptr, out);
        scan_f32_inplace<<<512, 64, 0, stream>>>(out, decay);
    } else {
        gemm_naive<<<dim3(N_DIM / 16, M_DIM / 16), dim3(16, 16), 0, stream>>>(X, Wt, bias, out);
        scan_f32_inplace<<<512, 64, 0, stream>>>(out, decay);
    }
}

// Round 2
// 365.267 us; speedup vs baseline: 1.0637x; 1.0637x over previous
//
#include <hip/hip_runtime.h>

// Problem constants: B=32, T=1024, IN=1024, OUT=1024
// M = B*T = 32768, K = IN = 1024, N = OUT = 1024
#define M_DIM 32768
#define N_DIM 1024
#define K_DIM 1024
#define T_DIM 1024
#define B_DIM 32
#define NCHUNK 8
#define CHUNK_T 128   // T_DIM / NCHUNK

typedef unsigned int uint32;
typedef __attribute__((ext_vector_type(8))) short short8;     // 8 bf16 = 4 VGPR (MFMA A/B frag)
typedef __attribute__((ext_vector_type(4))) float floatx4;    // MFMA C/D frag

__device__ __forceinline__ unsigned short f2bf(float f) {
    uint32 u = __float_as_uint(f);
    uint32 r = u + 0x7fffu + ((u >> 16) & 1u);
    return (unsigned short)(r >> 16);
}

__device__ __forceinline__ float bf2f(unsigned short h) {
    return __uint_as_float(((uint32)h) << 16);
}

__device__ __forceinline__ void async_load16(const void* g, void* s) {
    __builtin_amdgcn_global_load_lds(
        (const __attribute__((address_space(1))) void*)g,
        (__attribute__((address_space(3))) void*)s,
        16, 0, 0);
}

// ---------------------------------------------------------------------------
// fp32 -> bf16 cast, 4 elems/thread
// ---------------------------------------------------------------------------
__global__ void cast_f32_bf16(const float* __restrict__ src,
                              unsigned short* __restrict__ dst, int n4) {
    int i = blockIdx.x * blockDim.x + threadIdx.x;
    if (i < n4) {
        float4 v = ((const float4*)src)[i];
        ushort4 o;
        o.x = f2bf(v.x); o.y = f2bf(v.y); o.z = f2bf(v.z); o.w = f2bf(v.w);
        ((ushort4*)dst)[i] = o;
    }
}

// ---------------------------------------------------------------------------
// bf16 MFMA GEMM: C[m,n] = sum_k A[m,k]*W[n,k] + bias[n]  (unchanged from R1)
// ---------------------------------------------------------------------------
__global__ __launch_bounds__(256) void gemm_mfma(
    const unsigned short* __restrict__ A,   // [M, K] bf16
    const unsigned short* __restrict__ Bw,  // [N, K] bf16
    const float* __restrict__ bias,         // [N]
    unsigned short* outBf,                  // [M, N] bf16 (or null)
    float* outF) {                          // [M, N] fp32 (or null)
    __shared__ unsigned short As[128 * 64];
    __shared__ unsigned short Bs[128 * 64];

    const int tid  = threadIdx.x;
    const int lane = tid & 63;
    const int wid  = tid >> 6;
    const int l15  = lane & 15;
    const int quad = lane >> 4;
    const int wm   = wid >> 1;
    const int wn   = wid & 1;
    const int bm0  = blockIdx.y * 128;
    const int bn0  = blockIdx.x * 128;

    floatx4 acc[4][4];
#pragma unroll
    for (int i = 0; i < 4; ++i)
#pragma unroll
        for (int j = 0; j < 4; ++j)
            acc[i][j] = (floatx4){0.f, 0.f, 0.f, 0.f};

    for (int kt = 0; kt < K_DIM / 64; ++kt) {
        const int k0 = kt * 64;
#pragma unroll
        for (int q = 0; q < 4; ++q) {
            int slot = q * 256 + tid;
            int row  = slot >> 3;
            int ch   = slot & 7;
            int sc   = ch ^ (row & 7);
            async_load16(A + (size_t)(bm0 + row) * K_DIM + k0 + sc * 8,
                         &As[(q * 256 + wid * 64) * 8]);
        }
#pragma unroll
        for (int q = 0; q < 4; ++q) {
            int slot = q * 256 + tid;
            int row  = slot >> 3;
            int ch   = slot & 7;
            int sc   = ch ^ (row & 7);
            async_load16(Bw + (size_t)(bn0 + row) * K_DIM + k0 + sc * 8,
                         &Bs[(q * 256 + wid * 64) * 8]);
        }
        __syncthreads();

#pragma unroll
        for (int ks = 0; ks < 2; ++ks) {
            short8 af[4], bfr[4];
#pragma unroll
            for (int i = 0; i < 4; ++i) {
                int r = wm * 64 + i * 16 + l15;
                int c = ks * 4 + quad;
                af[i] = *(const short8*)&As[r * 64 + ((c ^ (r & 7)) * 8)];
            }
#pragma unroll
            for (int j = 0; j < 4; ++j) {
                int r = wn * 64 + j * 16 + l15;
                int c = ks * 4 + quad;
                bfr[j] = *(const short8*)&Bs[r * 64 + ((c ^ (r & 7)) * 8)];
            }
#pragma unroll
            for (int i = 0; i < 4; ++i)
#pragma unroll
                for (int j = 0; j < 4; ++j)
                    acc[i][j] = __builtin_amdgcn_mfma_f32_16x16x32_bf16(
                        af[i], bfr[j], acc[i][j], 0, 0, 0);
        }
        __syncthreads();
    }

#pragma unroll
    for (int j = 0; j < 4; ++j) {
        int col = bn0 + wn * 64 + j * 16 + l15;
        float bb = bias[col];
#pragma unroll
        for (int i = 0; i < 4; ++i) {
            int rowb = bm0 + wm * 64 + i * 16 + quad * 4;
#pragma unroll
            for (int r = 0; r < 4; ++r) {
                float v = acc[i][j][r] + bb;
                size_t idx = (size_t)(rowb + r) * N_DIM + col;
                if (outBf) outBf[idx] = f2bf(v);
                else       outF[idx]  = v;
            }
        }
    }
}

// ---------------------------------------------------------------------------
// Reduce-then-scan over T, exact decomposition.
// Thread <-> (b, chunk, o): o = tid&1023, chunk = (tid>>10)&7, b = tid>>13.
// Within a wave, b/chunk are uniform and o spans 64 consecutive -> coalesced.
//
// Phase 1: scan own 128-step chunk with u=0, write chunk-end carry only.
// Phase 2: U = sum_{i<chunk} a^(128*(chunk-i)) carry_i  (via U = c_i + A*U,
//          A = a^128 by 7 squarings), then rescan chunk from U, write out.
// ---------------------------------------------------------------------------
__global__ __launch_bounds__(256) void scan_carry(
    const unsigned short* __restrict__ cur,   // [M, N] bf16
    const float* __restrict__ decay,
    float* __restrict__ carry) {              // [B, NCHUNK, N]
    int tid = blockIdx.x * 256 + threadIdx.x;       // 0 .. 262143
    int o     = tid & (N_DIM - 1);
    int chunk = (tid >> 10) & (NCHUNK - 1);
    int b     = tid >> 13;
    size_t base = ((size_t)b * T_DIM + (size_t)chunk * CHUNK_T) * N_DIM + o;
    float a = decay[o];
    float c = 1.f - a;
    float u = 0.f;
    for (int t0 = 0; t0 < CHUNK_T; t0 += 16) {
        float x[16];
#pragma unroll
        for (int k = 0; k < 16; ++k)
            x[k] = bf2f(cur[base + (size_t)(t0 + k) * N_DIM]);
#pragma unroll
        for (int k = 0; k < 16; ++k)
            u = a * u + c * x[k];
    }
    carry[((size_t)b * NCHUNK + chunk) * N_DIM + o] = u;
}

__global__ __launch_bounds__(256) void scan_apply(
    const unsigned short* __restrict__ cur,   // [M, N] bf16
    const float* __restrict__ decay,
    const float* __restrict__ carry,          // [B, NCHUNK, N]
    float* __restrict__ out) {                // [M, N] fp32
    int tid = blockIdx.x * 256 + threadIdx.x;
    int o     = tid & (N_DIM - 1);
    int chunk = (tid >> 10) & (NCHUNK - 1);
    int b     = tid >> 13;
    size_t base = ((size_t)b * T_DIM + (size_t)chunk * CHUNK_T) * N_DIM + o;
    float a = decay[o];
    float c = 1.f - a;

    float A = a;
#pragma unroll
    for (int i = 0; i < 7; ++i) A *= A;       // a^128

    float U = 0.f;
    const float* cb = carry + (size_t)b * NCHUNK * N_DIM + o;
    for (int i = 0; i < chunk; ++i)           // wave-uniform trip count
        U = cb[(size_t)i * N_DIM] + A * U;

    float u = U;
    for (int t0 = 0; t0 < CHUNK_T; t0 += 16) {
        float x[16];
#pragma unroll
        for (int k = 0; k < 16; ++k)
            x[k] = bf2f(cur[base + (size_t)(t0 + k) * N_DIM]);
#pragma unroll
        for (int k = 0; k < 16; ++k) {
            u = a * u + c * x[k];
            out[base + (size_t)(t0 + k) * N_DIM] = u;
        }
    }
}

// ---------------------------------------------------------------------------
// Fallbacks (only used if workspace too small for the bf16 path)
// ---------------------------------------------------------------------------
__global__ void scan_f32_inplace(float* __restrict__ buf,
                                 const float* __restrict__ decay) {
    int tid = blockIdx.x * 64 + threadIdx.x;
    int o = tid & (N_DIM - 1);
    size_t base = ((size_t)(tid >> 10) << 20) + o;
    float a = decay[o];
    float c = 1.f - a;
    float u = 0.f;
    for (int t0 = 0; t0 < 1024; t0 += 16) {
        float x[16];
#pragma unroll
        for (int k = 0; k < 16; ++k)
            x[k] = buf[base + (size_t)(t0 + k) * N_DIM];
#pragma unroll
        for (int k = 0; k < 16; ++k) {
            u = a * u + c * x[k];
            buf[base + (size_t)(t0 + k) * N_DIM] = u;
        }
    }
}

__global__ void gemm_naive(const float* __restrict__ X, const float* __restrict__ W,
                           const float* __restrict__ bias, float* __restrict__ out) {
    __shared__ float As[16][17], Bs[16][17];
    int tx = threadIdx.x, ty = threadIdx.y;
    int m0 = blockIdx.y * 16, n0 = blockIdx.x * 16;
    float acc = 0.f;
    for (int k0 = 0; k0 < K_DIM; k0 += 16) {
        As[ty][tx] = X[(size_t)(m0 + ty) * K_DIM + k0 + tx];
        Bs[ty][tx] = W[(size_t)(n0 + ty) * K_DIM + k0 + tx];
        __syncthreads();
#pragma unroll
        for (int kk = 0; kk < 16; ++kk) acc += As[ty][kk] * Bs[tx][kk];
        __syncthreads();
    }
    out[(size_t)(m0 + ty) * N_DIM + n0 + tx] = acc + bias[n0 + tx];
}

// ---------------------------------------------------------------------------
extern "C" void kernel_launch(void* const* d_in, const int* in_sizes, int n_in,
                              void* d_out, int out_size, void* d_ws, size_t ws_size,
                              hipStream_t stream) {
    const float* X     = (const float*)d_in[0];  // [B,T,IN]  = [M,K]
    const float* Wt    = (const float*)d_in[1];  // [OUT,IN]  = [N,K]
    const float* bias  = (const float*)d_in[2];  // [OUT]
    const float* decay = (const float*)d_in[3];  // [OUT]
    float* out = (float*)d_out;                  // [B,T,OUT] = [M,N]

    const size_t A_bytes  = (size_t)M_DIM * K_DIM * 2;            // 64 MB
    const size_t W_bytes  = (size_t)N_DIM * K_DIM * 2;            // 2 MB
    const size_t C_bytes  = (size_t)M_DIM * N_DIM * 2;            // 64 MB
    const size_t cr_bytes = (size_t)B_DIM * NCHUNK * N_DIM * 4;   // 1 MB
    const size_t need_mid  = A_bytes + W_bytes;
    const size_t need_full = A_bytes + W_bytes + C_bytes + cr_bytes;

    if (ws_size >= need_full) {
        unsigned short* Abf = (unsigned short*)d_ws;
        unsigned short* Wbf = (unsigned short*)((char*)d_ws + A_bytes);
        unsigned short* Cbf = (unsigned short*)((char*)d_ws + A_bytes + W_bytes);
        float* carry = (float*)((char*)d_ws + A_bytes + W_bytes + C_bytes);
        cast_f32_bf16<<<(M_DIM * K_DIM / 4 + 255) / 256, 256, 0, stream>>>(X, Abf, M_DIM * K_DIM / 4);
        cast_f32_bf16<<<(N_DIM * K_DIM / 4 + 255) / 256, 256, 0, stream>>>(Wt, Wbf, N_DIM * K_DIM / 4);
        gemm_mfma<<<dim3(N_DIM / 128, M_DIM / 128), 256, 0, stream>>>(Abf, Wbf, bias, Cbf, nullptr);
        const int scan_threads = B_DIM * NCHUNK * N_DIM;          // 262144
        scan_carry<<<scan_threads / 256, 256, 0, stream>>>(Cbf, decay, carry);
        scan_apply<<<scan_threads / 256, 256, 0, stream>>>(Cbf, decay, carry, out);
    } else if (ws_size >= need_mid) {
        unsigned short* Abf = (unsigned short*)d_ws;
        unsigned short* Wbf = (unsigned short*)((char*)d_ws + A_bytes);
        cast_f32_bf16<<<(M_DIM * K_DIM / 4 + 255) / 256, 256, 0, stream>>>(X, Abf, M_DIM * K_DIM / 4);
        cast_f32_bf16<<<(N_DIM * K_DIM / 4 + 255) / 256, 256, 0, stream>>>(Wt, Wbf, N_DIM * K_DIM / 4);
        gemm_mfma<<<dim3(N_DIM / 128, M_DIM / 128), 256, 0, stream>>>(Abf, Wbf, bias, nullptr, out);
        scan_f32_inplace<<<512, 64, 0, stream>>>(out, decay);
    } else {
        gemm_naive<<<dim3(N_DIM / 16, M_DIM / 16), dim3(16, 16), 0, stream>>>(X, Wt, bias, out);
        scan_f32_inplace<<<512, 64, 0, stream>>>(out, decay);
    }
}

// Round 3
// 354.425 us; speedup vs baseline: 1.0963x; 1.0306x over previous
//
#include <hip/hip_runtime.h>

// Problem constants: B=32, T=1024, IN=1024, OUT=1024
// M = B*T = 32768, K = IN = 1024, N = OUT = 1024
#define M_DIM 32768
#define N_DIM 1024
#define K_DIM 1024
#define T_DIM 1024
#define B_DIM 32
#define NCHUNK 8
#define CHUNK_T 128   // T_DIM / NCHUNK

typedef unsigned int uint32;
typedef __attribute__((ext_vector_type(8))) short short8;       // 8 bf16 (MFMA A/B frag)
typedef __attribute__((ext_vector_type(8))) unsigned short ushort8v;
typedef __attribute__((ext_vector_type(4))) float floatx4;      // MFMA C/D frag

__device__ __forceinline__ unsigned short f2bf(float f) {
    uint32 u = __float_as_uint(f);
    uint32 r = u + 0x7fffu + ((u >> 16) & 1u);
    return (unsigned short)(r >> 16);
}

__device__ __forceinline__ float bf2f(unsigned short h) {
    return __uint_as_float(((uint32)h) << 16);
}

__device__ __forceinline__ void async_load16(const void* g, void* s) {
    __builtin_amdgcn_global_load_lds(
        (const __attribute__((address_space(1))) void*)g,
        (__attribute__((address_space(3))) void*)s,
        16, 0, 0);
}

// ---------------------------------------------------------------------------
// fp32 -> bf16 cast, 8 elems/thread (16B store)
// ---------------------------------------------------------------------------
__global__ void cast_f32_bf16_x8(const float* __restrict__ src,
                                 unsigned short* __restrict__ dst, int n8) {
    int i = blockIdx.x * blockDim.x + threadIdx.x;
    if (i < n8) {
        const float4* s4 = (const float4*)src;
        float4 v0 = s4[(size_t)i * 2];
        float4 v1 = s4[(size_t)i * 2 + 1];
        ushort8v o;
        o[0] = f2bf(v0.x); o[1] = f2bf(v0.y); o[2] = f2bf(v0.z); o[3] = f2bf(v0.w);
        o[4] = f2bf(v1.x); o[5] = f2bf(v1.y); o[6] = f2bf(v1.z); o[7] = f2bf(v1.w);
        ((ushort8v*)dst)[i] = o;
    }
}

// ---------------------------------------------------------------------------
// bf16 MFMA GEMM: C[m,n] = sum_k A[m,k]*W[n,k] + bias[n]
// 128x128 tile, BK=64. XCD-aware swizzle: dispatch round-robins linear block
// id across 8 XCDs (heuristic), so map L = (xcd, s): xcd owns M-panels
// [xcd*32, xcd*32+32), iterating all 8 N-tiles of a panel consecutively ->
// each A-panel is fetched into exactly one XCD's L2.
// ---------------------------------------------------------------------------
__global__ __launch_bounds__(256) void gemm_mfma(
    const unsigned short* __restrict__ A,   // [M, K] bf16
    const unsigned short* __restrict__ Bw,  // [N, K] bf16
    const float* __restrict__ bias,         // [N]
    unsigned short* outBf,                  // [M, N] bf16 (or null)
    float* outF) {                          // [M, N] fp32 (or null)
    __shared__ unsigned short As[128 * 64];
    __shared__ unsigned short Bs[128 * 64];

    const int tid  = threadIdx.x;
    const int lane = tid & 63;
    const int wid  = tid >> 6;
    const int l15  = lane & 15;
    const int quad = lane >> 4;
    const int wm   = wid >> 1;
    const int wn   = wid & 1;

    // XCD-aware remap (grid is (8, 256) -> L in [0, 2048))
    const int L    = blockIdx.y * gridDim.x + blockIdx.x;
    const int xcd  = L & 7;
    const int s    = L >> 3;
    const int bn0  = (s & 7) * 128;                 // N-tile
    const int bm0  = (xcd * 32 + (s >> 3)) * 128;   // M-panel

    floatx4 acc[4][4];
#pragma unroll
    for (int i = 0; i < 4; ++i)
#pragma unroll
        for (int j = 0; j < 4; ++j)
            acc[i][j] = (floatx4){0.f, 0.f, 0.f, 0.f};

    for (int kt = 0; kt < K_DIM / 64; ++kt) {
        const int k0 = kt * 64;
#pragma unroll
        for (int q = 0; q < 4; ++q) {
            int slot = q * 256 + tid;
            int row  = slot >> 3;
            int ch   = slot & 7;
            int sc   = ch ^ (row & 7);   // XOR swizzle folded into source addr
            async_load16(A + (size_t)(bm0 + row) * K_DIM + k0 + sc * 8,
                         &As[(q * 256 + wid * 64) * 8]);
        }
#pragma unroll
        for (int q = 0; q < 4; ++q) {
            int slot = q * 256 + tid;
            int row  = slot >> 3;
            int ch   = slot & 7;
            int sc   = ch ^ (row & 7);
            async_load16(Bw + (size_t)(bn0 + row) * K_DIM + k0 + sc * 8,
                         &Bs[(q * 256 + wid * 64) * 8]);
        }
        __syncthreads();

#pragma unroll
        for (int ks = 0; ks < 2; ++ks) {
            short8 af[4], bfr[4];
#pragma unroll
            for (int i = 0; i < 4; ++i) {
                int r = wm * 64 + i * 16 + l15;
                int c = ks * 4 + quad;
                af[i] = *(const short8*)&As[r * 64 + ((c ^ (r & 7)) * 8)];
            }
#pragma unroll
            for (int j = 0; j < 4; ++j) {
                int r = wn * 64 + j * 16 + l15;
                int c = ks * 4 + quad;
                bfr[j] = *(const short8*)&Bs[r * 64 + ((c ^ (r & 7)) * 8)];
            }
#pragma unroll
            for (int i = 0; i < 4; ++i)
#pragma unroll
                for (int j = 0; j < 4; ++j)
                    acc[i][j] = __builtin_amdgcn_mfma_f32_16x16x32_bf16(
                        af[i], bfr[j], acc[i][j], 0, 0, 0);
        }
        __syncthreads();
    }

    // C/D layout: col = lane&15, row = quad*4 + reg
#pragma unroll
    for (int j = 0; j < 4; ++j) {
        int col = bn0 + wn * 64 + j * 16 + l15;
        float bb = bias[col];
#pragma unroll
        for (int i = 0; i < 4; ++i) {
            int rowb = bm0 + wm * 64 + i * 16 + quad * 4;
#pragma unroll
            for (int r = 0; r < 4; ++r) {
                float v = acc[i][j][r] + bb;
                size_t idx = (size_t)(rowb + r) * N_DIM + col;
                if (outBf) outBf[idx] = f2bf(v);
                else       outF[idx]  = v;
            }
        }
    }
}

// ---------------------------------------------------------------------------
// Reduce-then-scan over T, 2-wide over o (dword = 2 bf16), unroll 32:
// 32 independent 256B/wave loads in flight (8KB/wave).
// Thread <-> (b, chunk, o2): o2 = tid&511 (o = 2*o2), chunk = (tid>>9)&7,
// b = tid>>12. 131072 threads = 2048 waves = 8 waves/CU.
// ---------------------------------------------------------------------------
__global__ __launch_bounds__(256) void scan_carry2(
    const uint32* __restrict__ cur32,         // [M, N/2] (bf16 pairs)
    const float* __restrict__ decay,
    float* __restrict__ carry) {              // [B, NCHUNK, N]
    int tid   = blockIdx.x * 256 + threadIdx.x;   // 0 .. 131071
    int o2    = tid & 511;
    int chunk = (tid >> 9) & (NCHUNK - 1);
    int b     = tid >> 12;
    int o     = o2 * 2;
    size_t base = ((size_t)b * T_DIM + (size_t)chunk * CHUNK_T) * (N_DIM / 2) + o2;
    float2 a2 = *(const float2*)&decay[o];
    float a0 = a2.x, a1 = a2.y;
    float c0 = 1.f - a0, c1 = 1.f - a1;
    float u0 = 0.f, u1 = 0.f;
    for (int t0 = 0; t0 < CHUNK_T; t0 += 32) {
        uint32 x[32];
#pragma unroll
        for (int k = 0; k < 32; ++k)
            x[k] = cur32[base + (size_t)(t0 + k) * (N_DIM / 2)];
#pragma unroll
        for (int k = 0; k < 32; ++k) {
            float lo = __uint_as_float(x[k] << 16);
            float hi = __uint_as_float(x[k] & 0xffff0000u);
            u0 = a0 * u0 + c0 * lo;
            u1 = a1 * u1 + c1 * hi;
        }
    }
    float2* cw = (float2*)&carry[((size_t)b * NCHUNK + chunk) * N_DIM + o];
    *cw = (float2){u0, u1};
}

__global__ __launch_bounds__(256) void scan_apply2(
    const uint32* __restrict__ cur32,         // [M, N/2] (bf16 pairs)
    const float* __restrict__ decay,
    const float* __restrict__ carry,          // [B, NCHUNK, N]
    float* __restrict__ out) {                // [M, N] fp32
    int tid   = blockIdx.x * 256 + threadIdx.x;
    int o2    = tid & 511;
    int chunk = (tid >> 9) & (NCHUNK - 1);
    int b     = tid >> 12;
    int o     = o2 * 2;
    size_t base = ((size_t)b * T_DIM + (size_t)chunk * CHUNK_T) * (N_DIM / 2) + o2;
    float2 a2 = *(const float2*)&decay[o];
    float a0 = a2.x, a1 = a2.y;
    float c0 = 1.f - a0, c1 = 1.f - a1;

    float A0 = a0, A1 = a1;
#pragma unroll
    for (int i = 0; i < 7; ++i) { A0 *= A0; A1 *= A1; }   // a^128

    float u0 = 0.f, u1 = 0.f;
    const float* cb = carry + (size_t)b * NCHUNK * N_DIM + o;
    for (int i = 0; i < chunk; ++i) {         // wave-uniform trip count
        float2 cv = *(const float2*)&cb[(size_t)i * N_DIM];
        u0 = cv.x + A0 * u0;
        u1 = cv.y + A1 * u1;
    }

    float2* out2 = (float2*)out;
    size_t obase = ((size_t)b * T_DIM + (size_t)chunk * CHUNK_T) * (N_DIM / 2) + o2;
    for (int t0 = 0; t0 < CHUNK_T; t0 += 32) {
        uint32 x[32];
#pragma unroll
        for (int k = 0; k < 32; ++k)
            x[k] = cur32[base + (size_t)(t0 + k) * (N_DIM / 2)];
#pragma unroll
        for (int k = 0; k < 32; ++k) {
            float lo = __uint_as_float(x[k] << 16);
            float hi = __uint_as_float(x[k] & 0xffff0000u);
            u0 = a0 * u0 + c0 * lo;
            u1 = a1 * u1 + c1 * hi;
            out2[obase + (size_t)(t0 + k) * (N_DIM / 2)] = (float2){u0, u1};
        }
    }
}

// ---------------------------------------------------------------------------
// Fallbacks (only used if workspace too small for the bf16 path)
// ---------------------------------------------------------------------------
__global__ void scan_f32_inplace(float* __restrict__ buf,
                                 const float* __restrict__ decay) {
    int tid = blockIdx.x * 64 + threadIdx.x;
    int o = tid & (N_DIM - 1);
    size_t base = ((size_t)(tid >> 10) << 20) + o;
    float a = decay[o];
    float c = 1.f - a;
    float u = 0.f;
    for (int t0 = 0; t0 < 1024; t0 += 16) {
        float x[16];
#pragma unroll
        for (int k = 0; k < 16; ++k)
            x[k] = buf[base + (size_t)(t0 + k) * N_DIM];
#pragma unroll
        for (int k = 0; k < 16; ++k) {
            u = a * u + c * x[k];
            buf[base + (size_t)(t0 + k) * N_DIM] = u;
        }
    }
}

__global__ void gemm_naive(const float* __restrict__ X, const float* __restrict__ W,
                           const float* __restrict__ bias, float* __restrict__ out) {
    __shared__ float As[16][17], Bs[16][17];
    int tx = threadIdx.x, ty = threadIdx.y;
    int m0 = blockIdx.y * 16, n0 = blockIdx.x * 16;
    float acc = 0.f;
    for (int k0 = 0; k0 < K_DIM; k0 += 16) {
        As[ty][tx] = X[(size_t)(m0 + ty) * K_DIM + k0 + tx];
        Bs[ty][tx] = W[(size_t)(n0 + ty) * K_DIM + k0 + tx];
        __syncthreads();
#pragma unroll
        for (int kk = 0; kk < 16; ++kk) acc += As[ty][kk] * Bs[tx][kk];
        __syncthreads();
    }
    out[(size_t)(m0 + ty) * N_DIM + n0 + tx] = acc + bias[n0 + tx];
}

// ---------------------------------------------------------------------------
extern "C" void kernel_launch(void* const* d_in, const int* in_sizes, int n_in,
                              void* d_out, int out_size, void* d_ws, size_t ws_size,
                              hipStream_t stream) {
    const float* X     = (const float*)d_in[0];  // [B,T,IN]  = [M,K]
    const float* Wt    = (const float*)d_in[1];  // [OUT,IN]  = [N,K]
    const float* bias  = (const float*)d_in[2];  // [OUT]
    const float* decay = (const float*)d_in[3];  // [OUT]
    float* out = (float*)d_out;                  // [B,T,OUT] = [M,N]

    const size_t A_bytes  = (size_t)M_DIM * K_DIM * 2;            // 64 MB
    const size_t W_bytes  = (size_t)N_DIM * K_DIM * 2;            // 2 MB
    const size_t C_bytes  = (size_t)M_DIM * N_DIM * 2;            // 64 MB
    const size_t cr_bytes = (size_t)B_DIM * NCHUNK * N_DIM * 4;   // 1 MB
    const size_t need_mid  = A_bytes + W_bytes;
    const size_t need_full = A_bytes + W_bytes + C_bytes + cr_bytes;

    if (ws_size >= need_full) {
        unsigned short* Abf = (unsigned short*)d_ws;
        unsigned short* Wbf = (unsigned short*)((char*)d_ws + A_bytes);
        unsigned short* Cbf = (unsigned short*)((char*)d_ws + A_bytes + W_bytes);
        float* carry = (float*)((char*)d_ws + A_bytes + W_bytes + C_bytes);
        cast_f32_bf16_x8<<<(M_DIM * K_DIM / 8 + 255) / 256, 256, 0, stream>>>(X, Abf, M_DIM * K_DIM / 8);
        cast_f32_bf16_x8<<<(N_DIM * K_DIM / 8 + 255) / 256, 256, 0, stream>>>(Wt, Wbf, N_DIM * K_DIM / 8);
        gemm_mfma<<<dim3(N_DIM / 128, M_DIM / 128), 256, 0, stream>>>(Abf, Wbf, bias, Cbf, nullptr);
        const int scan_threads = B_DIM * NCHUNK * N_DIM / 2;      // 131072
        scan_carry2<<<scan_threads / 256, 256, 0, stream>>>((const uint32*)Cbf, decay, carry);
        scan_apply2<<<scan_threads / 256, 256, 0, stream>>>((const uint32*)Cbf, decay, carry, out);
    } else if (ws_size >= need_mid) {
        unsigned short* Abf = (unsigned short*)d_ws;
        unsigned short* Wbf = (unsigned short*)((char*)d_ws + A_bytes);
        cast_f32_bf16_x8<<<(M_DIM * K_DIM / 8 + 255) / 256, 256, 0, stream>>>(X, Abf, M_DIM * K_DIM / 8);
        cast_f32_bf16_x8<<<(N_DIM * K_DIM / 8 + 255) / 256, 256, 0, stream>>>(Wt, Wbf, N_DIM * K_DIM / 8);
        gemm_mfma<<<dim3(N_DIM / 128, M_DIM / 128), 256, 0, stream>>>(Abf, Wbf, bias, nullptr, out);
        scan_f32_inplace<<<512, 64, 0, stream>>>(out, decay);
    } else {
        gemm_naive<<<dim3(N_DIM / 16, M_DIM / 16), dim3(16, 16), 0, stream>>>(X, Wt, bias, out);
        scan_f32_inplace<<<512, 64, 0, stream>>>(out, decay);
    }
}